// Round 10
// baseline (361.512 us; speedup 1.0000x reference)
//
#include <hip/hip_runtime.h>
#include <hip/hip_bf16.h>
#include <math.h>

#define NN 32768
#define UU 16384
#define EE 1048576
#define NB 512      // dst buckets
#define NPB 64      // nodes per bucket (NN/NB)
#define SB2 512     // scatter blocks (full CU coverage)
#define EPB2 2048   // edges per scatter block (EE/SB2)
#define CAP 2560    // bucket capacity (mean 2048, sigma~45 -> 11 sigma slack)

typedef __attribute__((ext_vector_type(8))) short bf16x8;
typedef __attribute__((ext_vector_type(4))) float f32x4;

__device__ __forceinline__ float sigf(float v) { return 1.0f / (1.0f + expf(-v)); }

// ---------------- Merged: scatter_fused (blocks 0..511) + prep_m (blocks 512..639) ----------------
__global__ __launch_bounds__(256) void prep_scatter_k(const int* __restrict__ e,
                                                      const float* __restrict__ h,
                                                      int* __restrict__ gcount,
                                                      uint2* __restrict__ sorted,
                                                      const int* __restrict__ x,
                                                      const float* __restrict__ emb,
                                                      const float* __restrict__ ggc,
                                                      float* __restrict__ m) {
    __shared__ int h1[NB], h2[NB], base[NB];
    __shared__ float w[256];
    if (blockIdx.x >= SB2) {
        // ---- prep_m: m = emb[x] @ ggc^T ----
        int pb = blockIdx.x - SB2;
        w[threadIdx.x] = ggc[threadIdx.x];
        __syncthreads();
        int i = pb * 256 + threadIdx.x;
        int xi = x[i];
        float xe[16];
        const float4* s4 = (const float4*)(emb + (size_t)xi * 16);
#pragma unroll
        for (int q = 0; q < 4; ++q) {
            float4 v = s4[q];
            xe[4*q] = v.x; xe[4*q+1] = v.y; xe[4*q+2] = v.z; xe[4*q+3] = v.w;
        }
        float o[16];
#pragma unroll
        for (int j = 0; j < 16; ++j) {
            float acc = 0.0f;
#pragma unroll
            for (int k = 0; k < 16; ++k) acc += xe[k] * w[j*16 + k];
            o[j] = acc;
        }
        float4* d4 = (float4*)(m + (size_t)i * 16);
#pragma unroll
        for (int q = 0; q < 4; ++q) d4[q] = make_float4(o[4*q], o[4*q+1], o[4*q+2], o[4*q+3]);
        return;
    }
    // ---- scatter_fused: hist -> global range reservation -> place ----
    for (int t = threadIdx.x; t < NB; t += 256) { h1[t] = 0; h2[t] = 0; }
    __syncthreads();
    int eb = blockIdx.x * EPB2;
    const int4*   sp = (const int4*)(e + eb);
    const int4*   dp = (const int4*)(e + EE + eb);
    const float4* wp = (const float4*)(h + eb);
#pragma unroll
    for (int k = 0; k < 2; ++k) {
        int4 d = dp[threadIdx.x + k * 256];
        atomicAdd(&h1[d.x >> 6], 1); atomicAdd(&h1[d.y >> 6], 1);
        atomicAdd(&h1[d.z >> 6], 1); atomicAdd(&h1[d.w >> 6], 1);
    }
    __syncthreads();
    for (int t = threadIdx.x; t < NB; t += 256) {
        int c = h1[t];
        base[t] = c ? atomicAdd(&gcount[t * 16], c) : 0;
    }
    __syncthreads();
#define PLACE(dv, sv, wv) { int b_ = (dv) >> 6; int off_ = atomicAdd(&h2[b_], 1); \
    sorted[(size_t)b_ * CAP + base[b_] + off_] = \
        make_uint2(((unsigned)(sv) << 6) | (unsigned)((dv) & 63), __float_as_uint(wv)); }
#pragma unroll
    for (int k = 0; k < 2; ++k) {
        int idx = threadIdx.x + k * 256;
        int4   s = sp[idx];
        int4   d = dp[idx];
        float4 wv = wp[idx];
        PLACE(d.x, s.x, wv.x) PLACE(d.y, s.y, wv.y)
        PLACE(d.z, s.z, wv.z) PLACE(d.w, s.w, wv.w)
    }
#undef PLACE
}

// ---------------- Fused: counting-sort + atomic-free aggregation + GRU + LSTM ----------------
__global__ __launch_bounds__(256) void aggnode_k(
    const uint2* __restrict__ sorted, const int* __restrict__ gcount,
    const float* __restrict__ m,
    const int* __restrict__ x, const float* __restrict__ emb,
    const float* __restrict__ h0g, const float* __restrict__ c0g,
    const float* __restrict__ gwi, const float* __restrict__ gwh,
    const float* __restrict__ gbi, const float* __restrict__ gbh,
    const float* __restrict__ lwi, const float* __restrict__ lwh,
    const float* __restrict__ lbi, const float* __restrict__ lbh,
    float* __restrict__ out_h, float* __restrict__ out_c, ushort* __restrict__ yb) {
    __shared__ uint2 sedge[CAP];
    __shared__ int   cnt[NPB], off[NPB], place[NPB];
    __shared__ float s_a[NPB * 17];
    __shared__ float s_ht[NPB * 17];
    __shared__ float s_gwi[768], s_gwh[768], s_gbi[48], s_gbh[48];
    __shared__ float s_lwi[2048], s_lwh[4096], s_lbi[128], s_lbh[128];

    int tid = threadIdx.x;
    if (tid < NPB) { cnt[tid] = 0; place[tid] = 0; }
    for (int t = tid; t < 768; t += 256) { s_gwi[t] = gwi[t]; s_gwh[t] = gwh[t]; }
    if (tid < 48) { s_gbi[tid] = gbi[tid]; s_gbh[tid] = gbh[tid]; }
    for (int t = tid; t < 2048; t += 256) s_lwi[t] = lwi[t];
    for (int t = tid; t < 4096; t += 256) s_lwh[t] = lwh[t];
    if (tid < 128) { s_lbi[tid] = lbi[tid]; s_lbh[tid] = lbh[tid]; }
    __syncthreads();

    int b = blockIdx.x;
    int nb = gcount[b * 16];
    const uint2* seg = sorted + (size_t)b * CAP;
    // ---- Phase A: count per dst-low ----
    for (int i = tid; i < nb; i += 256)
        atomicAdd(&cnt[seg[i].x & 63], 1);
    __syncthreads();
    // ---- Phase B: exclusive scan (wave 0) ----
    if (tid < 64) {
        int c0 = cnt[tid];
        int c = c0;
#pragma unroll
        for (int o = 1; o < 64; o <<= 1) {
            int v = __shfl_up(c, o, 64);
            if (tid >= o) c += v;
        }
        off[tid] = c - c0;
    }
    __syncthreads();
    // ---- Phase C: place edges into LDS, grouped by dst-low ----
    for (int i = tid; i < nb; i += 256) {
        uint2 ev = seg[i];
        int dl = ev.x & 63;
        int pos = off[dl] + atomicAdd(&place[dl], 1);
        sedge[pos] = ev;
    }
    __syncthreads();

    int n  = tid >> 2;
    int p  = tid & 3;
    int gn = b * NPB + n;
    // ---- Phase D: segmented reduction, 4 threads/node, no atomics ----
    {
        int s0 = off[n], deg = cnt[n];
        float a0 = 0.f, a1 = 0.f, a2 = 0.f, a3 = 0.f;
        const float4* m4 = (const float4*)m;
        for (int i = s0; i < s0 + deg; ++i) {
            uint2 ev = sedge[i];
            float w = __uint_as_float(ev.y);
            int src = ev.x >> 6;
            float4 v = m4[src * 4 + p];
            a0 += v.x * w; a1 += v.y * w; a2 += v.z * w; a3 += v.w * w;
        }
        float inv = 1.0f / fmaxf((float)deg, 1.0f);
        float* ap = &s_a[n * 17 + p * 4];
        ap[0] = a0 * inv; ap[1] = a1 * inv; ap[2] = a2 * inv; ap[3] = a3 * inv;
    }
    int xi = x[gn];
    float xe[16];
    {
        const float4* p2 = (const float4*)(emb + (size_t)xi * 16);
#pragma unroll
        for (int q = 0; q < 4; ++q) {
            float4 v = p2[q];
            xe[4*q] = v.x; xe[4*q+1] = v.y; xe[4*q+2] = v.z; xe[4*q+3] = v.w;
        }
    }
    __syncthreads();
    // ---- Phase E: GRU — 4 features per thread ----
    {
        const float* a = &s_a[n * 17];
#pragma unroll
        for (int ff = 0; ff < 4; ++ff) {
            int f = p * 4 + ff;
            float ir = s_gbi[f],    iz = s_gbi[16+f], in_ = s_gbi[32+f];
            float hr = s_gbh[f],    hz = s_gbh[16+f], hn  = s_gbh[32+f];
#pragma unroll
            for (int k = 0; k < 16; ++k) {
                float av = a[k], xv = xe[k];
                ir  += av * s_gwi[f*16 + k];
                iz  += av * s_gwi[(16+f)*16 + k];
                in_ += av * s_gwi[(32+f)*16 + k];
                hr  += xv * s_gwh[f*16 + k];
                hz  += xv * s_gwh[(16+f)*16 + k];
                hn  += xv * s_gwh[(32+f)*16 + k];
            }
            float r = sigf(ir + hr);
            float z = sigf(iz + hz);
            float nn2 = tanhf(in_ + r * hn);
            s_ht[n * 17 + f] = (1.0f - z) * nn2 + z * xe[f];
        }
    }
    __syncthreads();
    // ---- Phase F: LSTM — 8 outputs per thread ----
    {
        float h0v[32];
        const float4* ph = (const float4*)(h0g + (size_t)gn * 32);
#pragma unroll
        for (int q = 0; q < 8; ++q) {
            float4 v = ph[q];
            h0v[4*q] = v.x; h0v[4*q+1] = v.y; h0v[4*q+2] = v.z; h0v[4*q+3] = v.w;
        }
        float htv[16];
#pragma unroll
        for (int k = 0; k < 16; ++k) htv[k] = s_ht[n * 17 + k];
        float c0v[8];
        {
            float4 ca = *(const float4*)(c0g + (size_t)gn * 32 + p * 8);
            float4 cb = *(const float4*)(c0g + (size_t)gn * 32 + p * 8 + 4);
            c0v[0]=ca.x; c0v[1]=ca.y; c0v[2]=ca.z; c0v[3]=ca.w;
            c0v[4]=cb.x; c0v[5]=cb.y; c0v[6]=cb.z; c0v[7]=cb.w;
        }
        float cnv[8], hnv[8];
        ushort yv[8];
#pragma unroll
        for (int jj = 0; jj < 8; ++jj) {
            int j = p * 8 + jj;
            float ig = s_lbi[j]      + s_lbh[j];
            float fg = s_lbi[32+j]   + s_lbh[32+j];
            float gg = s_lbi[64+j]   + s_lbh[64+j];
            float og = s_lbi[96+j]   + s_lbh[96+j];
#pragma unroll
            for (int k = 0; k < 16; ++k) {
                float hv = htv[k];
                ig += hv * s_lwi[j*16 + k];
                fg += hv * s_lwi[(32+j)*16 + k];
                gg += hv * s_lwi[(64+j)*16 + k];
                og += hv * s_lwi[(96+j)*16 + k];
            }
#pragma unroll
            for (int k = 0; k < 32; ++k) {
                float hv = h0v[k];
                ig += hv * s_lwh[j*32 + k];
                fg += hv * s_lwh[(32+j)*32 + k];
                gg += hv * s_lwh[(64+j)*32 + k];
                og += hv * s_lwh[(96+j)*32 + k];
            }
            float cn  = sigf(fg) * c0v[jj] + sigf(ig) * tanhf(gg);
            float hn2 = sigf(og) * tanhf(cn);
            cnv[jj] = cn; hnv[jj] = hn2;
            __hip_bfloat16 t = __float2bfloat16(fmaxf(hn2, 0.0f));
            yv[jj] = *(ushort*)&t;
        }
        size_t ob = (size_t)gn * 32 + p * 8;
        *(float4*)(out_c + ob)     = make_float4(cnv[0],cnv[1],cnv[2],cnv[3]);
        *(float4*)(out_c + ob + 4) = make_float4(cnv[4],cnv[5],cnv[6],cnv[7]);
        *(float4*)(out_h + ob)     = make_float4(hnv[0],hnv[1],hnv[2],hnv[3]);
        *(float4*)(out_h + ob + 4) = make_float4(hnv[4],hnv[5],hnv[6],hnv[7]);
        uint4 yq;
        yq.x = (unsigned)yv[0] | ((unsigned)yv[1] << 16);
        yq.y = (unsigned)yv[2] | ((unsigned)yv[3] << 16);
        yq.z = (unsigned)yv[4] | ((unsigned)yv[5] << 16);
        yq.w = (unsigned)yv[6] | ((unsigned)yv[7] << 16);
        *(uint4*)(yb + ob) = yq;
    }
}

// ---------------- Kernel D: scores = y_u @ y_i^T via bf16 MFMA ----------------
// Slab mapping: 1024 blocks x (16 rows x 16384 cols); all blocks co-resident
// (4/CU pinned via launch_bounds), each writes one contiguous 1 MB slab.
// Inner wave tile identical to R6: 16x256 per chunk + LDS-transpose epilogue.
__global__ __launch_bounds__(256, 4) void scores_mfma_k(const ushort* __restrict__ yb,
                                                        float* __restrict__ out) {
    __shared__ float tr[4][16][68];
    int tid = threadIdx.x;
    int w = tid >> 6, l = tid & 63;
    int row0 = blockIdx.x * 16;   // 1024 row-blocks of 16 rows
    int lr = l & 15;
    int G  = l >> 4;              // 0..3
    int lk = G << 3;              // 0,8,16,24
    bf16x8 a = *(const bf16x8*)(yb + (size_t)(row0 + lr) * 32 + lk);
    float* lw = &tr[w][0][0];
#pragma unroll 1
    for (int chunk = 0; chunk < 16; ++chunk) {
        int col0 = w * 4096 + chunk * 256;
        const ushort* yi = yb + (size_t)(UU + col0) * 32;
        f32x4 acc[16];
#pragma unroll
        for (int ct = 0; ct < 16; ++ct) {
            bf16x8 b = *(const bf16x8*)(yi + (size_t)(ct * 16 + lr) * 32 + lk);
            acc[ct] = __builtin_amdgcn_mfma_f32_16x16x32_bf16(a, b, (f32x4){0.0f,0.0f,0.0f,0.0f}, 0, 0, 0);
        }
#pragma unroll
        for (int g = 0; g < 4; ++g) {
#pragma unroll
            for (int ct2 = 0; ct2 < 4; ++ct2)
#pragma unroll
                for (int r = 0; r < 4; ++r)
                    lw[(G * 4 + r) * 68 + ct2 * 16 + lr] = acc[g * 4 + ct2][r];
#pragma unroll
            for (int i = 0; i < 4; ++i) {
                int rl = 4 * i + G;
                float4 v = *(const float4*)&lw[rl * 68 + lr * 4];
                *(float4*)(out + (size_t)(row0 + rl) * UU + col0 + g * 64 + lr * 4) = v;
            }
        }
    }
}

extern "C" void kernel_launch(void* const* d_in, const int* in_sizes, int n_in,
                              void* d_out, int out_size, void* d_ws, size_t ws_size,
                              hipStream_t stream) {
    const int*   x   = (const int*)d_in[0];
    const int*   e   = (const int*)d_in[1];
    const float* h   = (const float*)d_in[2];
    const float* h0  = (const float*)d_in[3];
    const float* c0  = (const float*)d_in[4];
    const float* emb = (const float*)d_in[5];
    const float* ggc = (const float*)d_in[6];
    const float* gwi = (const float*)d_in[7];
    const float* gwh = (const float*)d_in[8];
    const float* gbi = (const float*)d_in[9];
    const float* gbh = (const float*)d_in[10];
    const float* lwi = (const float*)d_in[11];
    const float* lwh = (const float*)d_in[12];
    const float* lbi = (const float*)d_in[13];
    const float* lbh = (const float*)d_in[14];

    float* out    = (float*)d_out;
    float* scores = out;
    float* out_h  = out + (size_t)UU * UU;
    float* out_c  = out_h + (size_t)NN * 32;

    char* ws = (char*)d_ws;
    float*  m       = (float*)(ws);                    // 2 MB
    ushort* yb      = (ushort*)(ws + (4u << 20));      // NN*32 bf16 = 2 MB
    int*    gcount  = (int*)  (ws + (8u << 20));       // 512 counters, 64B-padded = 32 KB

    // 512*2560*8B = 10.5 MB sorted-edge scratch inside the scores output
    // region (fully overwritten by scores_mfma_k afterwards).
    uint2* sorted  = (uint2*)((char*)d_out + (512u << 20));

    hipMemsetAsync(gcount, 0, NB * 16 * sizeof(int), stream);
    prep_scatter_k<<<SB2 + NN / 256, 256, 0, stream>>>(e, h, gcount, sorted, x, emb, ggc, m);
    aggnode_k<<<NB, 256, 0, stream>>>(sorted, gcount, m, x, emb, h0, c0,
                                      gwi, gwh, gbi, gbh,
                                      lwi, lwh, lbi, lbh,
                                      out_h, out_c, yb);
    scores_mfma_k<<<1024, 256, 0, stream>>>(yb, scores);
}

// Round 11
// 320.564 us; speedup vs baseline: 1.1277x; 1.1277x over previous
//
#include <hip/hip_runtime.h>
#include <hip/hip_bf16.h>
#include <math.h>

#define NN 32768
#define UU 16384
#define EE 1048576
#define NB 512      // dst buckets
#define NPB 64      // nodes per bucket (NN/NB)
#define SB2 512     // scatter blocks (full CU coverage)
#define EPB2 2048   // edges per scatter block (EE/SB2)
#define CAP 2560    // bucket capacity (mean 2048, sigma~45 -> 11 sigma slack)

typedef __attribute__((ext_vector_type(8))) short bf16x8;
typedef __attribute__((ext_vector_type(4))) float f32x4;

__device__ __forceinline__ float sigf(float v) { return 1.0f / (1.0f + expf(-v)); }

// ---------------- Merged: scatter_fused (blocks 0..511) + prep_m (blocks 512..639) ----------------
__global__ __launch_bounds__(256) void prep_scatter_k(const int* __restrict__ e,
                                                      const float* __restrict__ h,
                                                      int* __restrict__ gcount,
                                                      uint2* __restrict__ sorted,
                                                      const int* __restrict__ x,
                                                      const float* __restrict__ emb,
                                                      const float* __restrict__ ggc,
                                                      float* __restrict__ m) {
    __shared__ int h1[NB], h2[NB], base[NB];
    __shared__ float w[256];
    if (blockIdx.x >= SB2) {
        // ---- prep_m: m = emb[x] @ ggc^T ----
        int pb = blockIdx.x - SB2;
        w[threadIdx.x] = ggc[threadIdx.x];
        __syncthreads();
        int i = pb * 256 + threadIdx.x;
        int xi = x[i];
        float xe[16];
        const float4* s4 = (const float4*)(emb + (size_t)xi * 16);
#pragma unroll
        for (int q = 0; q < 4; ++q) {
            float4 v = s4[q];
            xe[4*q] = v.x; xe[4*q+1] = v.y; xe[4*q+2] = v.z; xe[4*q+3] = v.w;
        }
        float o[16];
#pragma unroll
        for (int j = 0; j < 16; ++j) {
            float acc = 0.0f;
#pragma unroll
            for (int k = 0; k < 16; ++k) acc += xe[k] * w[j*16 + k];
            o[j] = acc;
        }
        float4* d4 = (float4*)(m + (size_t)i * 16);
#pragma unroll
        for (int q = 0; q < 4; ++q) d4[q] = make_float4(o[4*q], o[4*q+1], o[4*q+2], o[4*q+3]);
        return;
    }
    // ---- scatter_fused: hist -> global range reservation -> place ----
    for (int t = threadIdx.x; t < NB; t += 256) { h1[t] = 0; h2[t] = 0; }
    __syncthreads();
    int eb = blockIdx.x * EPB2;
    const int4*   sp = (const int4*)(e + eb);
    const int4*   dp = (const int4*)(e + EE + eb);
    const float4* wp = (const float4*)(h + eb);
#pragma unroll
    for (int k = 0; k < 2; ++k) {
        int4 d = dp[threadIdx.x + k * 256];
        atomicAdd(&h1[d.x >> 6], 1); atomicAdd(&h1[d.y >> 6], 1);
        atomicAdd(&h1[d.z >> 6], 1); atomicAdd(&h1[d.w >> 6], 1);
    }
    __syncthreads();
    for (int t = threadIdx.x; t < NB; t += 256) {
        int c = h1[t];
        base[t] = c ? atomicAdd(&gcount[t * 16], c) : 0;
    }
    __syncthreads();
#define PLACE(dv, sv, wv) { int b_ = (dv) >> 6; int off_ = atomicAdd(&h2[b_], 1); \
    sorted[(size_t)b_ * CAP + base[b_] + off_] = \
        make_uint2(((unsigned)(sv) << 6) | (unsigned)((dv) & 63), __float_as_uint(wv)); }
#pragma unroll
    for (int k = 0; k < 2; ++k) {
        int idx = threadIdx.x + k * 256;
        int4   s = sp[idx];
        int4   d = dp[idx];
        float4 wv = wp[idx];
        PLACE(d.x, s.x, wv.x) PLACE(d.y, s.y, wv.y)
        PLACE(d.z, s.z, wv.z) PLACE(d.w, s.w, wv.w)
    }
#undef PLACE
}

// ---------------- Fused: counting-sort + atomic-free aggregation + GRU + LSTM ----------------
__global__ __launch_bounds__(256) void aggnode_k(
    const uint2* __restrict__ sorted, const int* __restrict__ gcount,
    const float* __restrict__ m,
    const int* __restrict__ x, const float* __restrict__ emb,
    const float* __restrict__ h0g, const float* __restrict__ c0g,
    const float* __restrict__ gwi, const float* __restrict__ gwh,
    const float* __restrict__ gbi, const float* __restrict__ gbh,
    const float* __restrict__ lwi, const float* __restrict__ lwh,
    const float* __restrict__ lbi, const float* __restrict__ lbh,
    float* __restrict__ out_h, float* __restrict__ out_c, ushort* __restrict__ yb) {
    __shared__ uint2 sedge[CAP];
    __shared__ int   cnt[NPB], off[NPB], place[NPB];
    __shared__ float s_a[NPB * 17];
    __shared__ float s_ht[NPB * 17];
    __shared__ float s_gwi[768], s_gwh[768], s_gbi[48], s_gbh[48];
    __shared__ float s_lwi[2048], s_lwh[4096], s_lbi[128], s_lbh[128];

    int tid = threadIdx.x;
    if (tid < NPB) { cnt[tid] = 0; place[tid] = 0; }
    for (int t = tid; t < 768; t += 256) { s_gwi[t] = gwi[t]; s_gwh[t] = gwh[t]; }
    if (tid < 48) { s_gbi[tid] = gbi[tid]; s_gbh[tid] = gbh[tid]; }
    for (int t = tid; t < 2048; t += 256) s_lwi[t] = lwi[t];
    for (int t = tid; t < 4096; t += 256) s_lwh[t] = lwh[t];
    if (tid < 128) { s_lbi[tid] = lbi[tid]; s_lbh[tid] = lbh[tid]; }
    __syncthreads();

    int b = blockIdx.x;
    int nb = gcount[b * 16];
    const uint2* seg = sorted + (size_t)b * CAP;
    // ---- Phase A: count per dst-low ----
    for (int i = tid; i < nb; i += 256)
        atomicAdd(&cnt[seg[i].x & 63], 1);
    __syncthreads();
    // ---- Phase B: exclusive scan (wave 0) ----
    if (tid < 64) {
        int c0 = cnt[tid];
        int c = c0;
#pragma unroll
        for (int o = 1; o < 64; o <<= 1) {
            int v = __shfl_up(c, o, 64);
            if (tid >= o) c += v;
        }
        off[tid] = c - c0;
    }
    __syncthreads();
    // ---- Phase C: place edges into LDS, grouped by dst-low ----
    for (int i = tid; i < nb; i += 256) {
        uint2 ev = seg[i];
        int dl = ev.x & 63;
        int pos = off[dl] + atomicAdd(&place[dl], 1);
        sedge[pos] = ev;
    }
    __syncthreads();

    int n  = tid >> 2;
    int p  = tid & 3;
    int gn = b * NPB + n;
    // ---- Phase D: segmented reduction, 4 threads/node, no atomics ----
    {
        int s0 = off[n], deg = cnt[n];
        float a0 = 0.f, a1 = 0.f, a2 = 0.f, a3 = 0.f;
        const float4* m4 = (const float4*)m;
        for (int i = s0; i < s0 + deg; ++i) {
            uint2 ev = sedge[i];
            float w = __uint_as_float(ev.y);
            int src = ev.x >> 6;
            float4 v = m4[src * 4 + p];
            a0 += v.x * w; a1 += v.y * w; a2 += v.z * w; a3 += v.w * w;
        }
        float inv = 1.0f / fmaxf((float)deg, 1.0f);
        float* ap = &s_a[n * 17 + p * 4];
        ap[0] = a0 * inv; ap[1] = a1 * inv; ap[2] = a2 * inv; ap[3] = a3 * inv;
    }
    int xi = x[gn];
    float xe[16];
    {
        const float4* p2 = (const float4*)(emb + (size_t)xi * 16);
#pragma unroll
        for (int q = 0; q < 4; ++q) {
            float4 v = p2[q];
            xe[4*q] = v.x; xe[4*q+1] = v.y; xe[4*q+2] = v.z; xe[4*q+3] = v.w;
        }
    }
    __syncthreads();
    // ---- Phase E: GRU — 4 features per thread ----
    {
        const float* a = &s_a[n * 17];
#pragma unroll
        for (int ff = 0; ff < 4; ++ff) {
            int f = p * 4 + ff;
            float ir = s_gbi[f],    iz = s_gbi[16+f], in_ = s_gbi[32+f];
            float hr = s_gbh[f],    hz = s_gbh[16+f], hn  = s_gbh[32+f];
#pragma unroll
            for (int k = 0; k < 16; ++k) {
                float av = a[k], xv = xe[k];
                ir  += av * s_gwi[f*16 + k];
                iz  += av * s_gwi[(16+f)*16 + k];
                in_ += av * s_gwi[(32+f)*16 + k];
                hr  += xv * s_gwh[f*16 + k];
                hz  += xv * s_gwh[(16+f)*16 + k];
                hn  += xv * s_gwh[(32+f)*16 + k];
            }
            float r = sigf(ir + hr);
            float z = sigf(iz + hz);
            float nn2 = tanhf(in_ + r * hn);
            s_ht[n * 17 + f] = (1.0f - z) * nn2 + z * xe[f];
        }
    }
    __syncthreads();
    // ---- Phase F: LSTM — 8 outputs per thread ----
    {
        float h0v[32];
        const float4* ph = (const float4*)(h0g + (size_t)gn * 32);
#pragma unroll
        for (int q = 0; q < 8; ++q) {
            float4 v = ph[q];
            h0v[4*q] = v.x; h0v[4*q+1] = v.y; h0v[4*q+2] = v.z; h0v[4*q+3] = v.w;
        }
        float htv[16];
#pragma unroll
        for (int k = 0; k < 16; ++k) htv[k] = s_ht[n * 17 + k];
        float c0v[8];
        {
            float4 ca = *(const float4*)(c0g + (size_t)gn * 32 + p * 8);
            float4 cb = *(const float4*)(c0g + (size_t)gn * 32 + p * 8 + 4);
            c0v[0]=ca.x; c0v[1]=ca.y; c0v[2]=ca.z; c0v[3]=ca.w;
            c0v[4]=cb.x; c0v[5]=cb.y; c0v[6]=cb.z; c0v[7]=cb.w;
        }
        float cnv[8], hnv[8];
        ushort yv[8];
#pragma unroll
        for (int jj = 0; jj < 8; ++jj) {
            int j = p * 8 + jj;
            float ig = s_lbi[j]      + s_lbh[j];
            float fg = s_lbi[32+j]   + s_lbh[32+j];
            float gg = s_lbi[64+j]   + s_lbh[64+j];
            float og = s_lbi[96+j]   + s_lbh[96+j];
#pragma unroll
            for (int k = 0; k < 16; ++k) {
                float hv = htv[k];
                ig += hv * s_lwi[j*16 + k];
                fg += hv * s_lwi[(32+j)*16 + k];
                gg += hv * s_lwi[(64+j)*16 + k];
                og += hv * s_lwi[(96+j)*16 + k];
            }
#pragma unroll
            for (int k = 0; k < 32; ++k) {
                float hv = h0v[k];
                ig += hv * s_lwh[j*32 + k];
                fg += hv * s_lwh[(32+j)*32 + k];
                gg += hv * s_lwh[(64+j)*32 + k];
                og += hv * s_lwh[(96+j)*32 + k];
            }
            float cn  = sigf(fg) * c0v[jj] + sigf(ig) * tanhf(gg);
            float hn2 = sigf(og) * tanhf(cn);
            cnv[jj] = cn; hnv[jj] = hn2;
            __hip_bfloat16 t = __float2bfloat16(fmaxf(hn2, 0.0f));
            yv[jj] = *(ushort*)&t;
        }
        size_t ob = (size_t)gn * 32 + p * 8;
        *(float4*)(out_c + ob)     = make_float4(cnv[0],cnv[1],cnv[2],cnv[3]);
        *(float4*)(out_c + ob + 4) = make_float4(cnv[4],cnv[5],cnv[6],cnv[7]);
        *(float4*)(out_h + ob)     = make_float4(hnv[0],hnv[1],hnv[2],hnv[3]);
        *(float4*)(out_h + ob + 4) = make_float4(hnv[4],hnv[5],hnv[6],hnv[7]);
        uint4 yq;
        yq.x = (unsigned)yv[0] | ((unsigned)yv[1] << 16);
        yq.y = (unsigned)yv[2] | ((unsigned)yv[3] << 16);
        yq.z = (unsigned)yv[4] | ((unsigned)yv[5] << 16);
        yq.w = (unsigned)yv[6] | ((unsigned)yv[7] << 16);
        *(uint4*)(yb + ob) = yq;
    }
}

// ---------------- Kernel D: scores = y_u @ y_i^T via bf16 MFMA ----------------
// R6/R9 mapping (measured best): 16384 blocks, 64x256 block tile,
// wave tile 16x256, LDS-transpose epilogue.
__global__ __launch_bounds__(256) void scores_mfma_k(const ushort* __restrict__ yb,
                                                     float* __restrict__ out) {
    __shared__ float tr[4][16][68];
    int tid = threadIdx.x;
    int w = tid >> 6, l = tid & 63;
    int bx = blockIdx.x & 63;     // 64 col-blocks of 256
    int by = blockIdx.x >> 6;     // 256 row-blocks of 64
    int row0 = by * 64 + w * 16;
    int col0 = bx * 256;
    int lr = l & 15;
    int lk = (l >> 4) << 3;       // 0,8,16,24
    bf16x8 a = *(const bf16x8*)(yb + (size_t)(row0 + lr) * 32 + lk);
    const ushort* yi = yb + (size_t)(UU + col0) * 32;
    f32x4 acc[16];
#pragma unroll
    for (int ct = 0; ct < 16; ++ct) {
        bf16x8 b = *(const bf16x8*)(yi + (size_t)(ct * 16 + lr) * 32 + lk);
        acc[ct] = __builtin_amdgcn_mfma_f32_16x16x32_bf16(a, b, (f32x4){0.0f,0.0f,0.0f,0.0f}, 0, 0, 0);
    }
    float* lw = &tr[w][0][0];
    int G = l >> 4;               // 0..3
#pragma unroll
    for (int g = 0; g < 4; ++g) {
#pragma unroll
        for (int ct2 = 0; ct2 < 4; ++ct2)
#pragma unroll
            for (int r = 0; r < 4; ++r)
                lw[(G * 4 + r) * 68 + ct2 * 16 + lr] = acc[g * 4 + ct2][r];
#pragma unroll
        for (int i = 0; i < 4; ++i) {
            int rl = 4 * i + G;
            float4 v = *(const float4*)&lw[rl * 68 + lr * 4];
            *(float4*)(out + (size_t)(row0 + rl) * UU + col0 + g * 64 + lr * 4) = v;
        }
    }
}

extern "C" void kernel_launch(void* const* d_in, const int* in_sizes, int n_in,
                              void* d_out, int out_size, void* d_ws, size_t ws_size,
                              hipStream_t stream) {
    const int*   x   = (const int*)d_in[0];
    const int*   e   = (const int*)d_in[1];
    const float* h   = (const float*)d_in[2];
    const float* h0  = (const float*)d_in[3];
    const float* c0  = (const float*)d_in[4];
    const float* emb = (const float*)d_in[5];
    const float* ggc = (const float*)d_in[6];
    const float* gwi = (const float*)d_in[7];
    const float* gwh = (const float*)d_in[8];
    const float* gbi = (const float*)d_in[9];
    const float* gbh = (const float*)d_in[10];
    const float* lwi = (const float*)d_in[11];
    const float* lwh = (const float*)d_in[12];
    const float* lbi = (const float*)d_in[13];
    const float* lbh = (const float*)d_in[14];

    float* out    = (float*)d_out;
    float* scores = out;
    float* out_h  = out + (size_t)UU * UU;
    float* out_c  = out_h + (size_t)NN * 32;

    char* ws = (char*)d_ws;
    float*  m       = (float*)(ws);                    // 2 MB
    ushort* yb      = (ushort*)(ws + (4u << 20));      // NN*32 bf16 = 2 MB
    int*    gcount  = (int*)  (ws + (8u << 20));       // 512 counters, 64B-padded = 32 KB

    // 512*2560*8B = 10.5 MB sorted-edge scratch inside the scores output
    // region (fully overwritten by scores_mfma_k afterwards).
    uint2* sorted  = (uint2*)((char*)d_out + (512u << 20));

    hipMemsetAsync(gcount, 0, NB * 16 * sizeof(int), stream);
    prep_scatter_k<<<SB2 + NN / 256, 256, 0, stream>>>(e, h, gcount, sorted, x, emb, ggc, m);
    aggnode_k<<<NB, 256, 0, stream>>>(sorted, gcount, m, x, emb, h0, c0,
                                      gwi, gwh, gbi, gbh,
                                      lwi, lwh, lbi, lbh,
                                      out_h, out_c, yb);
    scores_mfma_k<<<16384, 256, 0, stream>>>(yb, scores);
}